// Round 12
// baseline (260.794 us; speedup 1.0000x reference)
//
#include <hip/hip_runtime.h>

typedef __attribute__((ext_vector_type(4))) float f32x4;
typedef __attribute__((ext_vector_type(8))) short bf16x8;
typedef __attribute__((ext_vector_type(4))) unsigned short u16x4;
typedef unsigned short u16;

#define MFMA16(a, b, c) __builtin_amdgcn_mfma_f32_16x16x32_bf16((a), (b), (c), 0, 0, 0)

#define T_SEQ 2048
#define DMODEL 2048
#define NHEADS 16
#define HDIM 128
#define WINDOW 256
#define MROWS 4096  // B*T
#define SC 0.08838834764831845f  // 1/sqrt(128)

__device__ __forceinline__ u16 f2bf(float f) {
  union { float f; unsigned u; } v; v.f = f;
  return (u16)((v.u + 0x7FFFu + ((v.u >> 16) & 1u)) >> 16);
}
__device__ __forceinline__ float bf2f(u16 u) {
  union { unsigned u; float f; } v; v.u = ((unsigned)u) << 16;
  return v.f;
}
__device__ __forceinline__ void gl_lds16(const u16* g, u16* l) {
  __builtin_amdgcn_global_load_lds((const __attribute__((address_space(1))) void*)(g),
                                   (__attribute__((address_space(3))) void*)(l), 16, 0, 0);
}

#define BAR __builtin_amdgcn_s_barrier()
#define FEN asm volatile("" ::: "memory")
#define VMC3 asm volatile("s_waitcnt vmcnt(3)" ::: "memory")
#define VMC2 asm volatile("s_waitcnt vmcnt(2)" ::: "memory")
#define VMC0 asm volatile("s_waitcnt vmcnt(0)" ::: "memory")

// ---------------------------------------------------------------------------
// Convert x, Wq, Wk, Wv, Wo (f32) -> contiguous bf16: [xb NX][wq][wk][wv][wo]
// ---------------------------------------------------------------------------
__global__ __launch_bounds__(256) void convert_all(const float* __restrict__ x,
                                                   const float* __restrict__ wq,
                                                   const float* __restrict__ wk,
                                                   const float* __restrict__ wv,
                                                   const float* __restrict__ wo,
                                                   u16* __restrict__ dst) {
  const size_t NX = (size_t)MROWS * DMODEL;
  const size_t NW = (size_t)DMODEL * DMODEL;
  const size_t chunks = (NX + 4 * NW) / 8;
  for (size_t ci = (size_t)blockIdx.x * 256 + threadIdx.x; ci < chunks;
       ci += (size_t)gridDim.x * 256) {
    const size_t off = ci * 8;
    const float* src;
    size_t so;
    if (off < NX) { src = x; so = off; }
    else {
      size_t rem = off - NX;
      if (rem < NW) { src = wq; so = rem; }
      else if (rem < 2 * NW) { src = wk; so = rem - NW; }
      else if (rem < 3 * NW) { src = wv; so = rem - 2 * NW; }
      else { src = wo; so = rem - 3 * NW; }
    }
    f32x4 a = *(const f32x4*)&src[so];
    f32x4 b = *(const f32x4*)&src[so + 4];
    bf16x8 o;
#pragma unroll
    for (int j = 0; j < 4; ++j) { o[j] = (short)f2bf(a[j]); o[j + 4] = (short)f2bf(b[j]); }
    *(bf16x8*)&dst[off] = o;
  }
}

// ---------------------------------------------------------------------------
// 2-phase QKV GEMM (R8 structure): C[4096,6144] = A @ Wcat^T.
// NEW: q columns (cg < DMODEL) are pre-scaled by SC = 1/sqrt(128) so the
// attention softmax works directly on scaled scores.
// ---------------------------------------------------------------------------
__global__ __launch_bounds__(512, 2) void gemm_qkv(const u16* __restrict__ A,
                                                   const u16* __restrict__ W,
                                                   u16* __restrict__ qk,
                                                   u16* __restrict__ vt) {
  __shared__ u16 lds[57344];
  const int tid = threadIdx.x, w = tid >> 6, lane = tid & 63;
  const int wm = w >> 2, wn = w & 3;
  const int fr = lane & 15, g = lane >> 4, g4 = g * 4;

  const int xcd = blockIdx.x & 7, bi = blockIdx.x >> 3;
  const int mt = bi >> 2, nt = xcd * 4 + (bi & 3);
  const int m0 = mt * 256, n0 = nt * 192;

  const int xs0 = (g ^ (fr & 7)) * 8;
  const int xs1 = xs0 ^ 32;
  const int aRow = wm * 128 + fr;
  const int bRow = wn * 48 + fr;

  const int sr = tid >> 3;
  const int scc = ((tid & 7) ^ (sr & 7)) * 8;
  const u16* pA0  = A + (size_t)(m0 + sr) * DMODEL + scc;
  const u16* pA1  = A + (size_t)(m0 + 64 + sr) * DMODEL + scc;
  const u16* pB0  = W + (size_t)(n0 + sr) * DMODEL + scc;
  const u16* pB0b = W + (size_t)(n0 + 64 + sr) * DMODEL + scc;
  const u16* pB1  = W + (size_t)(n0 + 128 + sr) * DMODEL + scc;

#define SAH(h, t, c)                                                                   \
  { gl_lds16(pA0 + (size_t)(h) * 128 * DMODEL + (t) * 64,                              \
             &lds[(c) * 16384 + (h) * 8192 + w * 512]);                                \
    gl_lds16(pA1 + (size_t)(h) * 128 * DMODEL + (t) * 64,                              \
             &lds[(c) * 16384 + (h) * 8192 + 4096 + w * 512]); }
#define SBH0(t, c)                                                                     \
  { gl_lds16(pB0 + (size_t)(t) * 64, &lds[32768 + (c) * 12288 + w * 512]);             \
    gl_lds16(pB0b + (size_t)(t) * 64, &lds[32768 + (c) * 12288 + 4096 + w * 512]); }
#define SBH1(t, c)                                                                     \
  { gl_lds16(pB1 + (size_t)(t) * 64, &lds[32768 + (c) * 12288 + 8192 + w * 512]); }

#define RD_AL(c)                                                                       \
  { _Pragma("unroll") for (int m_ = 0; m_ < 4; ++m_) {                                 \
      af[m_][0] = *(const bf16x8*)&lds[(c) * 16384 + (aRow + m_ * 16) * 64 + xs0];     \
      af[m_][1] = *(const bf16x8*)&lds[(c) * 16384 + (aRow + m_ * 16) * 64 + xs1]; } }
#define RD_AH(c)                                                                       \
  { _Pragma("unroll") for (int m_ = 0; m_ < 4; ++m_) {                                 \
      af[m_][0] = *(const bf16x8*)&lds[(c) * 16384 + (aRow + 64 + m_ * 16) * 64 + xs0];\
      af[m_][1] = *(const bf16x8*)&lds[(c) * 16384 + (aRow + 64 + m_ * 16) * 64 + xs1]; } }
#define RD_B(c)                                                                        \
  { _Pragma("unroll") for (int n_ = 0; n_ < 3; ++n_) {                                 \
      bfr[n_][0] = *(const bf16x8*)&lds[32768 + (c) * 12288 + (bRow + n_ * 16) * 64 + xs0]; \
      bfr[n_][1] = *(const bf16x8*)&lds[32768 + (c) * 12288 + (bRow + n_ * 16) * 64 + xs1]; } }

#define MMQ(MB)                                                                        \
  { __builtin_amdgcn_s_setprio(1);                                                    \
    _Pragma("unroll") for (int kc_ = 0; kc_ < 2; ++kc_)                                \
      _Pragma("unroll") for (int m_ = 0; m_ < 4; ++m_)                                 \
        _Pragma("unroll") for (int n_ = 0; n_ < 3; ++n_)                               \
          acc[(MB) + m_][n_] = MFMA16(af[m_][kc_], bfr[n_][kc_], acc[(MB) + m_][n_]);  \
    __builtin_amdgcn_s_setprio(0); }

  bf16x8 af[4][2], bfr[3][2];
  f32x4 acc[8][3];
#pragma unroll
  for (int i = 0; i < 8; ++i)
#pragma unroll
    for (int j = 0; j < 3; ++j) acc[i][j] = (f32x4){0.f, 0.f, 0.f, 0.f};

  SAH(0, 0, 0); SAH(1, 0, 0);
  SBH0(0, 0); SBH1(0, 0);
  SBH0(1, 1); SBH1(1, 1);
  VMC3; BAR;

#pragma unroll 1
  for (int i = 0; i < 15; ++i) {
    const int t0 = 2 * i;
    RD_AL(0); RD_B(0); SAH(0, t0 + 1, 1); SAH(1, t0 + 1, 1);
    FEN; BAR; MMQ(0); FEN; BAR;
    RD_AH(0); SBH0(t0 + 2, 0); SBH1(t0 + 2, 0);
    VMC3; BAR; MMQ(4); FEN; BAR;
    RD_AL(1); RD_B(1); SAH(0, t0 + 2, 0); SAH(1, t0 + 2, 0);
    FEN; BAR; MMQ(0); FEN; BAR;
    RD_AH(1); SBH0(t0 + 3, 1); SBH1(t0 + 3, 1);
    VMC3; BAR; MMQ(4); FEN; BAR;
  }
  RD_AL(0); RD_B(0); SAH(0, 31, 1); SAH(1, 31, 1);
  FEN; BAR; MMQ(0); FEN; BAR;
  RD_AH(0);
  VMC0; BAR; MMQ(4); FEN; BAR;
  RD_AL(1); RD_B(1);
  FEN; BAR; MMQ(0); FEN; BAR;
  RD_AH(1);
  FEN; BAR; MMQ(4);

#pragma unroll
  for (int mi = 0; mi < 8; ++mi)
#pragma unroll
    for (int ni = 0; ni < 3; ++ni) {
      const int row0 = m0 + wm * 128 + mi * 16 + g4;
      const int cg = n0 + wn * 48 + ni * 16 + fr;
      if (cg < 2 * DMODEL) {
        const float qs = (cg < DMODEL) ? SC : 1.0f;  // pre-scale q columns
#pragma unroll
        for (int r = 0; r < 4; ++r)
          qk[(size_t)(row0 + r) * (2 * DMODEL) + cg] = f2bf(acc[mi][ni][r] * qs);
      } else {
        const int cc = cg - 2 * DMODEL;
        const int hh = cc >> 7, d = cc & 127;
        const int bb = row0 >> 11, tl = row0 & 2047;
        u16x4 w4;
#pragma unroll
        for (int r = 0; r < 4; ++r) w4[r] = f2bf(acc[mi][ni][r]);
        *(u16x4*)&vt[((size_t)(bb * NHEADS + hh) * HDIM + d) * T_SEQ + tl] = w4;
      }
    }
#undef SAH
#undef SBH0
#undef SBH1
#undef RD_AL
#undef RD_AH
#undef RD_B
#undef MMQ
}

// ---------------------------------------------------------------------------
// 2-phase out-proj GEMM (unchanged, known-good R8).
// ---------------------------------------------------------------------------
__global__ __launch_bounds__(512, 2) void gemm_out(const u16* __restrict__ A,
                                                   const u16* __restrict__ W0,
                                                   float* __restrict__ outf) {
  __shared__ u16 lds2[49152];
  const int tid = threadIdx.x, w = tid >> 6, lane = tid & 63;
  const int wm = w >> 2, wn = w & 3;
  const int fr = lane & 15, g = lane >> 4, g4 = g * 4;

  const int xcd = blockIdx.x & 7, bi = blockIdx.x >> 3;
  const int mt = bi >> 1, nt = xcd * 2 + (bi & 1);
  const int m0 = mt * 256, n0 = nt * 128;

  const int xs0 = (g ^ (fr & 7)) * 8;
  const int xs1 = xs0 ^ 32;
  const int aRow = wm * 128 + fr;
  const int bRow = wn * 32 + fr;

  const int sr = tid >> 3;
  const int scc = ((tid & 7) ^ (sr & 7)) * 8;
  const u16* pA0  = A + (size_t)(m0 + sr) * DMODEL + scc;
  const u16* pA1  = A + (size_t)(m0 + 64 + sr) * DMODEL + scc;
  const u16* pB0  = W0 + (size_t)(n0 + sr) * DMODEL + scc;
  const u16* pB0b = W0 + (size_t)(n0 + 64 + sr) * DMODEL + scc;

#define S2A(h, t, c)                                                                   \
  { gl_lds16(pA0 + (size_t)(h) * 128 * DMODEL + (t) * 64,                              \
             &lds2[(c) * 16384 + (h) * 8192 + w * 512]);                               \
    gl_lds16(pA1 + (size_t)(h) * 128 * DMODEL + (t) * 64,                              \
             &lds2[(c) * 16384 + (h) * 8192 + 4096 + w * 512]); }
#define S2B(t, c)                                                                      \
  { gl_lds16(pB0 + (size_t)(t) * 64, &lds2[32768 + (c) * 8192 + w * 512]);             \
    gl_lds16(pB0b + (size_t)(t) * 64, &lds2[32768 + (c) * 8192 + 4096 + w * 512]); }

#define R2AL(c)                                                                        \
  { _Pragma("unroll") for (int m_ = 0; m_ < 4; ++m_) {                                 \
      af[m_][0] = *(const bf16x8*)&lds2[(c) * 16384 + (aRow + m_ * 16) * 64 + xs0];    \
      af[m_][1] = *(const bf16x8*)&lds2[(c) * 16384 + (aRow + m_ * 16) * 64 + xs1]; } }
#define R2AH(c)                                                                        \
  { _Pragma("unroll") for (int m_ = 0; m_ < 4; ++m_) {                                 \
      af[m_][0] = *(const bf16x8*)&lds2[(c) * 16384 + (aRow + 64 + m_ * 16) * 64 + xs0]; \
      af[m_][1] = *(const bf16x8*)&lds2[(c) * 16384 + (aRow + 64 + m_ * 16) * 64 + xs1]; } }
#define R2B(c)                                                                         \
  { _Pragma("unroll") for (int n_ = 0; n_ < 2; ++n_) {                                 \
      bfr[n_][0] = *(const bf16x8*)&lds2[32768 + (c) * 8192 + (bRow + n_ * 16) * 64 + xs0]; \
      bfr[n_][1] = *(const bf16x8*)&lds2[32768 + (c) * 8192 + (bRow + n_ * 16) * 64 + xs1]; } }

#define M2(MB)                                                                         \
  { __builtin_amdgcn_s_setprio(1);                                                    \
    _Pragma("unroll") for (int kc_ = 0; kc_ < 2; ++kc_)                                \
      _Pragma("unroll") for (int m_ = 0; m_ < 4; ++m_)                                 \
        _Pragma("unroll") for (int n_ = 0; n_ < 2; ++n_)                               \
          acc[(MB) + m_][n_] = MFMA16(af[m_][kc_], bfr[n_][kc_], acc[(MB) + m_][n_]);  \
    __builtin_amdgcn_s_setprio(0); }

  bf16x8 af[4][2], bfr[2][2];
  f32x4 acc[8][2];
#pragma unroll
  for (int i = 0; i < 8; ++i)
#pragma unroll
    for (int j = 0; j < 2; ++j) acc[i][j] = (f32x4){0.f, 0.f, 0.f, 0.f};

  S2A(0, 0, 0); S2A(1, 0, 0);
  S2B(0, 0);
  S2B(1, 1);
  VMC2; BAR;

#pragma unroll 1
  for (int i = 0; i < 15; ++i) {
    const int t0 = 2 * i;
    R2AL(0); R2B(0); S2A(0, t0 + 1, 1); S2A(1, t0 + 1, 1);
    FEN; BAR; M2(0); FEN; BAR;
    R2AH(0); S2B(t0 + 2, 0);
    VMC2; BAR; M2(4); FEN; BAR;
    R2AL(1); R2B(1); S2A(0, t0 + 2, 0); S2A(1, t0 + 2, 0);
    FEN; BAR; M2(0); FEN; BAR;
    R2AH(1); S2B(t0 + 3, 1);
    VMC2; BAR; M2(4); FEN; BAR;
  }
  R2AL(0); R2B(0); S2A(0, 31, 1); S2A(1, 31, 1);
  FEN; BAR; M2(0); FEN; BAR;
  R2AH(0);
  VMC0; BAR; M2(4); FEN; BAR;
  R2AL(1); R2B(1);
  FEN; BAR; M2(0); FEN; BAR;
  R2AH(1);
  FEN; BAR; M2(4);

#pragma unroll
  for (int mi = 0; mi < 8; ++mi)
#pragma unroll
    for (int ni = 0; ni < 2; ++ni) {
      const int row0 = m0 + wm * 128 + mi * 16 + g4;
      const int c = n0 + wn * 32 + ni * 16 + fr;
#pragma unroll
      for (int r = 0; r < 4; ++r)
        outf[(size_t)(row0 + r) * DMODEL + c] = acc[mi][ni][r];
    }
#undef S2A
#undef S2B
#undef R2AL
#undef R2AH
#undef R2B
#undef M2
}

// ---------------------------------------------------------------------------
// Striped flash attention, QB=128, 8 waves, KVB=64, CHAIN-CAPPED at 8 iters.
// Grid (64, 16, 2). Even h: bx<64 -> qt=15-(bx>>2), ci=bx&3; n=2qt+2 tiles,
// nc=ceil(n/8) chunks; ci>=nc returns. nc==1 (qt<=3) writes direct; else
// partial chunk [ci*8, min(ci*8+7, 2qt+1)]. Odd h: bx<16 -> qt=15-bx, banded.
// Q is PRE-SCALED by 1/sqrt(d) (gemm_qkv epilogue) -> no SC in softmax.
// gl_lds dbuf K/V, XOR granule swizzle, 1 barrier/iter, defer-max thr 8.
// Partials: 36 slots per (b,eh): qt4-7 -> base (qt-4)*2 (2 chunks);
// qt8-11 -> 8+(qt-8)*3 (3); qt12-15 -> 20+(qt-12)*4 (4). 576 slots total.
// ---------------------------------------------------------------------------
#define QB 128
#define KVB 64

__global__ __launch_bounds__(512, 4) void attn_kernel(const u16* __restrict__ qk,
                                                      const u16* __restrict__ vt,
                                                      u16* __restrict__ op,
                                                      u16* __restrict__ pO,
                                                      float* __restrict__ pm,
                                                      float* __restrict__ pl) {
  __shared__ u16 lds[40960];  // 80 KB

  const int bx = blockIdx.x, h = blockIdx.y, b = blockIdx.z;
  const bool isglobal = (h & 1) == 0;
  int qt, klo, khi, sidx = 0;
  bool partial = false;
  if (isglobal) {
    qt = 15 - (bx >> 2);
    const int ci = bx & 3;
    const int n = 2 * qt + 2;
    const int nc = (n + 7) >> 3;
    if (ci >= nc) return;
    klo = ci * 8;
    khi = min(klo + 7, 2 * qt + 1);
    partial = nc > 1;
    if (partial) {
      const int base = (qt < 8) ? (qt - 4) * 2 : (qt < 12 ? 8 + (qt - 8) * 3 : 20 + (qt - 12) * 4);
      sidx = (b * 8 + (h >> 1)) * 36 + base + ci;
    }
  } else {
    if (bx >= 16) return;
    qt = 15 - bx;
    const int lo_ = qt * QB - (WINDOW - 1);
    klo = lo_ > 0 ? (lo_ >> 6) : 0;
    khi = 2 * qt + 1;
  }

  const int tid = threadIdx.x, wave = tid >> 6, lane = tid & 63;
  const int fr = lane & 15, g = lane >> 4, g4 = g * 4;
  const int xk = fr & 7;
  const int q0 = qt * QB;
  const size_t baseq = (size_t)b * T_SEQ * (2 * DMODEL) + (size_t)h * HDIM;
  const size_t basek = baseq + DMODEL;
  const size_t basev = (size_t)(b * NHEADS + h) * HDIM * T_SEQ;
  const size_t baseo = (size_t)b * T_SEQ * DMODEL + (size_t)h * HDIM;

  // Q fragments (B-operand of swapped QK; row = fr = q-row); pre-scaled by SC
  bf16x8 qf[4];
  {
    const int qrow = q0 + wave * 16 + fr;
#pragma unroll
    for (int ds = 0; ds < 4; ++ds)
      qf[ds] = *(const bf16x8*)&qk[baseq + (size_t)qrow * (2 * DMODEL) + ds * 32 + g * 8];
  }

  float mrun = -1e30f, lrun = 0.f;
  f32x4 o[8];
#pragma unroll
  for (int dt = 0; dt < 8; ++dt) o[dt] = (f32x4){0.f, 0.f, 0.f, 0.f};

  // gl_lds staging constants (pre-swizzled per-lane global sources)
  const int j0 = wave * 2, j1 = wave * 2 + 1;
  const int gi0 = j0 * 64 + lane, gi1 = j1 * 64 + lane;
  const int kr0 = gi0 >> 4, kc0 = (gi0 & 15) ^ (kr0 & 7);
  const int kr1 = gi1 >> 4, kc1 = (gi1 & 15) ^ (kr1 & 7);
  const u16* pK0 = qk + basek + (size_t)kr0 * (2 * DMODEL) + kc0 * 8;
  const u16* pK1 = qk + basek + (size_t)kr1 * (2 * DMODEL) + kc1 * 8;
  const int d0 = gi0 >> 3, vs0 = (gi0 & 7) ^ (d0 & 7);
  const int d1 = gi1 >> 3, vs1 = (gi1 & 7) ^ (d1 & 7);
  const u16* pV0 = vt + basev + (size_t)d0 * T_SEQ + vs0 * 8;
  const u16* pV1 = vt + basev + (size_t)d1 * T_SEQ + vs1 * 8;

#define STAGE(KT, c)                                                                   \
  { gl_lds16(pK0 + (size_t)(KT) * (KVB * 2 * DMODEL), &lds[(c) * 8192 + j0 * 512]);    \
    gl_lds16(pK1 + (size_t)(KT) * (KVB * 2 * DMODEL), &lds[(c) * 8192 + j1 * 512]);    \
    gl_lds16(pV0 + (KT) * KVB, &lds[16384 + (c) * 8192 + j0 * 512]);                   \
    gl_lds16(pV1 + (KT) * KVB, &lds[16384 + (c) * 8192 + j1 * 512]); }

  u16* Pw = &lds[32768 + wave * 1024];
  const int qg = q0 + wave * 16 + fr;

  STAGE(klo, klo & 1);
  VMC0; BAR;

  for (int kt = klo; kt <= khi; ++kt) {
    const int c = kt & 1;
    const bool more = kt < khi;
    if (more) STAGE(kt + 1, c ^ 1);
    const u16* Kc = &lds[c * 8192];
    const u16* Vc = &lds[16384 + c * 8192];

    // ---- S = K Q^T (swapped): lane holds q=fr, kv = kk*16 + g4 + reg ----
    f32x4 s[4];
    __builtin_amdgcn_s_setprio(1);
#pragma unroll
    for (int kk = 0; kk < 4; ++kk) {
      f32x4 a = (f32x4){0.f, 0.f, 0.f, 0.f};
#pragma unroll
      for (int ds = 0; ds < 4; ++ds) {
        const int r = kk * 16 + fr;
        bf16x8 kf = *(const bf16x8*)&Kc[r * 128 + (((ds * 4 + g) ^ xk) << 3)];
        a = MFMA16(kf, qf[ds], a);
      }
      s[kk] = a;
    }
    __builtin_amdgcn_s_setprio(0);

    // ---- masked online softmax (scaled domain), defer-max ----
    float sv[16];
    float pmax = -1e30f;
#pragma unroll
    for (int kk = 0; kk < 4; ++kk)
#pragma unroll
      for (int reg = 0; reg < 4; ++reg) {
        const int cg = kt * KVB + kk * 16 + g4 + reg;
        const bool allowed = (cg <= qg) && (isglobal || cg >= qg - (WINDOW - 1));
        const float v = allowed ? s[kk][reg] : -1e30f;
        sv[kk * 4 + reg] = v;
        pmax = fmaxf(pmax, v);
      }
    pmax = fmaxf(pmax, __shfl_xor(pmax, 16, 64));
    pmax = fmaxf(pmax, __shfl_xor(pmax, 32, 64));
    const bool resc = !__all(pmax - mrun <= 8.0f);  // T13
    float fac = 1.f;
    if (resc) {
      const float nm = fmaxf(mrun, pmax);
      fac = __expf(mrun - nm);
      mrun = nm;
    }
    float rs = 0.f;
    u16 pb[16];
#pragma unroll
    for (int i = 0; i < 16; ++i) {
      const float p = (sv[i] > -5e29f) ? __expf(sv[i] - mrun) : 0.f;
      rs += p;
      pb[i] = f2bf(p);
    }
    rs += __shfl_xor(rs, 16, 64);
    rs += __shfl_xor(rs, 32, 64);
    lrun = lrun * fac + rs;

    // P -> per-wave LDS (swizzled 8B writes; row = q = fr)
#pragma unroll
    for (int kk = 0; kk < 4; ++kk) {
      u16x4 wv;
      wv[0] = pb[kk * 4]; wv[1] = pb[kk * 4 + 1]; wv[2] = pb[kk * 4 + 2]; wv[3] = pb[kk * 4 + 3];
      *(u16x4*)&Pw[fr * 64 + (((2 * kk + (g >> 1)) ^ xk) << 3) + (g & 1) * 4] = wv;
    }

    if (resc) {
      float ff[4];
#pragma unroll
      for (int r = 0; r < 4; ++r) ff[r] = __shfl(fac, g4 + r, 64);
#pragma unroll
      for (int dt = 0; dt < 8; ++dt)
#pragma unroll
        for (int r = 0; r < 4; ++r) o[dt][r] *= ff[r];
    }

    // ---- O += P V ----
    bf16x8 pf0 = *(const bf16x8*)&Pw[fr * 64 + ((g ^ xk) << 3)];
    bf16x8 pf1 = *(const bf16x8*)&Pw[fr * 64 + (((4 + g) ^ xk) << 3)];
    __builtin_amdgcn_s_setprio(1);
#pragma unroll
    for (int dt = 0; dt < 8; ++dt) {
      const int d = dt * 16 + fr;
      bf16x8 vf0 = *(const bf16x8*)&Vc[d * 64 + ((g ^ xk) << 3)];
      bf16x8 vf1 = *(const bf16x8*)&Vc[d * 64 + (((4 + g) ^ xk) << 3)];
      o[dt] = MFMA16(pf0, vf0, o[dt]);
      o[dt] = MFMA16(pf1, vf1, o[dt]);
    }
    __builtin_amdgcn_s_setprio(0);

    FEN;
    VMC0;
    BAR;
  }

  if (!partial) {
    const float inv = 1.0f / lrun;
    float iv[4];
#pragma unroll
    for (int r = 0; r < 4; ++r) iv[r] = __shfl(inv, g4 + r, 64);
#pragma unroll
    for (int r = 0; r < 4; ++r) {
      const int qrow = q0 + wave * 16 + g4 + r;
#pragma unroll
      for (int dt = 0; dt < 8; ++dt)
        op[baseo + (size_t)qrow * DMODEL + dt * 16 + fr] = f2bf(o[dt][r] * iv[r]);
    }
  } else {
    const size_t sb = (size_t)sidx * QB;
#pragma unroll
    for (int r = 0; r < 4; ++r) {
      const size_t row = sb + wave * 16 + g4 + r;
#pragma unroll
      for (int dt = 0; dt < 8; ++dt)
        pO[row * HDIM + dt * 16 + fr] = f2bf(o[dt][r]);
    }
    if (lane < 16) {
      pm[sb + wave * 16 + lane] = mrun;
      pl[sb + wave * 16 + lane] = lrun;
    }
  }
#undef STAGE
}

// ---------------------------------------------------------------------------
// Merge nc in {2,3,4} partials per (b, even h, qt>=4). Grid 192 x 256 thr.
// x = (b*8 + eh)*12 + (qt-4). Scaled domain (no SC).
// ---------------------------------------------------------------------------
__global__ __launch_bounds__(256) void merge_kernel(const u16* __restrict__ pO,
                                                    const float* __restrict__ pm,
                                                    const float* __restrict__ pl,
                                                    u16* __restrict__ op) {
  const int x = blockIdx.x;  // 0..191
  const int qtm4 = x % 12, beh = x / 12;
  const int eh = beh & 7, b = beh >> 3;
  const int h = eh * 2, qt = 4 + qtm4;
  const int nc = (qt < 8) ? 2 : (qt < 12 ? 3 : 4);
  const int base = (qt < 8) ? (qt - 4) * 2 : (qt < 12 ? 8 + (qt - 8) * 3 : 20 + (qt - 12) * 4);
  const int s0 = beh * 36 + base;

  for (int i = 0; i < 8; ++i) {
    const int vidx = threadIdx.x + i * 256;  // 0..2047
    const int row = vidx >> 4, d8 = (vidx & 15) * 8;
    float mv[4], lv[4], wv[4];
    float mm = -1e30f;
    for (int c = 0; c < nc; ++c) {
      mv[c] = pm[(size_t)(s0 + c) * QB + row];
      lv[c] = pl[(size_t)(s0 + c) * QB + row];
      mm = fmaxf(mm, mv[c]);
    }
    float lsum = 0.f;
    for (int c = 0; c < nc; ++c) { wv[c] = __expf(mv[c] - mm); lsum += lv[c] * wv[c]; }
    const float inv = 1.0f / lsum;
    float a8[8] = {0.f, 0.f, 0.f, 0.f, 0.f, 0.f, 0.f, 0.f};
    for (int c = 0; c < nc; ++c) {
      bf16x8 a = *(const bf16x8*)&pO[((size_t)(s0 + c) * QB + row) * HDIM + d8];
#pragma unroll
      for (int j = 0; j < 8; ++j) a8[j] += bf2f((u16)a[j]) * wv[c];
    }
    bf16x8 r;
#pragma unroll
    for (int j = 0; j < 8; ++j) r[j] = (short)f2bf(a8[j] * inv);
    *(bf16x8*)&op[((size_t)(b * T_SEQ + qt * QB + row)) * DMODEL + h * HDIM + d8] = r;
  }
}

// ---------------------------------------------------------------------------
extern "C" void kernel_launch(void* const* d_in, const int* in_sizes, int n_in,
                              void* d_out, int out_size, void* d_ws, size_t ws_size,
                              hipStream_t stream) {
  (void)in_sizes; (void)n_in; (void)out_size; (void)ws_size;
  const float* x  = (const float*)d_in[0];
  const float* Wq = (const float*)d_in[1];
  const float* Wk = (const float*)d_in[2];
  const float* Wv = (const float*)d_in[3];
  const float* Wo = (const float*)d_in[4];

  const size_t NX = (size_t)MROWS * DMODEL;
  const size_t NW = (size_t)DMODEL * DMODEL;
  u16* ws  = (u16*)d_ws;
  u16* xb  = ws;                 // bf16 x; later attention output
  u16* wqb = ws + NX;            // [wq|wk|wv] contiguous = Wcat[6144][2048]
  u16* wkb = wqb + NW;
  u16* wvb = wkb + NW;
  u16* wob = wvb + NW;
  u16* qkb = wob + NW;                          // [4096][4096]
  u16* vtb = qkb + (size_t)MROWS * 2 * DMODEL;  // [32][128][2048]

  // partials reuse dead wq/wk/wv region: 576 slots x 128 rows x 128 d
  u16*   pO = wqb;                               // 18.9 MB
  float* pm = (float*)(wqb + (size_t)576 * QB * HDIM);
  float* pl = pm + 576 * QB;                     // total 19.5 MB < 25.2 MB dead

  convert_all<<<2048, 256, 0, stream>>>(x, Wq, Wk, Wv, Wo, ws);

  gemm_qkv<<<512, 512, 0, stream>>>(xb, wqb, qkb, vtb);

  attn_kernel<<<dim3(64, NHEADS, 2), 512, 0, stream>>>(qkb, vtb, xb, pO, pm, pl);

  merge_kernel<<<192, 256, 0, stream>>>(pO, pm, pl, xb);

  gemm_out<<<256, 512, 0, stream>>>(xb, wob, (float*)d_out);
}

// Round 13
// 246.636 us; speedup vs baseline: 1.0574x; 1.0574x over previous
//
#include <hip/hip_runtime.h>

typedef __attribute__((ext_vector_type(4))) float f32x4;
typedef __attribute__((ext_vector_type(8))) short bf16x8;
typedef __attribute__((ext_vector_type(4))) unsigned short u16x4;
typedef unsigned short u16;

#define MFMA16(a, b, c) __builtin_amdgcn_mfma_f32_16x16x32_bf16((a), (b), (c), 0, 0, 0)

#define T_SEQ 2048
#define DMODEL 2048
#define NHEADS 16
#define HDIM 128
#define WINDOW 256
#define MROWS 4096  // B*T
#define SC 0.08838834764831845f  // 1/sqrt(128)

__device__ __forceinline__ u16 f2bf(float f) {
  union { float f; unsigned u; } v; v.f = f;
  return (u16)((v.u + 0x7FFFu + ((v.u >> 16) & 1u)) >> 16);
}
__device__ __forceinline__ float bf2f(u16 u) {
  union { unsigned u; float f; } v; v.u = ((unsigned)u) << 16;
  return v.f;
}
__device__ __forceinline__ void gl_lds16(const u16* g, u16* l) {
  __builtin_amdgcn_global_load_lds((const __attribute__((address_space(1))) void*)(g),
                                   (__attribute__((address_space(3))) void*)(l), 16, 0, 0);
}

#define BAR __builtin_amdgcn_s_barrier()
#define FEN asm volatile("" ::: "memory")
#define VMC3 asm volatile("s_waitcnt vmcnt(3)" ::: "memory")
#define VMC2 asm volatile("s_waitcnt vmcnt(2)" ::: "memory")
#define VMC0 asm volatile("s_waitcnt vmcnt(0)" ::: "memory")

// ---------------------------------------------------------------------------
// Convert x, Wq, Wk, Wv, Wo (f32) -> contiguous bf16: [xb NX][wq][wk][wv][wo]
// ---------------------------------------------------------------------------
__global__ __launch_bounds__(256) void convert_all(const float* __restrict__ x,
                                                   const float* __restrict__ wq,
                                                   const float* __restrict__ wk,
                                                   const float* __restrict__ wv,
                                                   const float* __restrict__ wo,
                                                   u16* __restrict__ dst) {
  const size_t NX = (size_t)MROWS * DMODEL;
  const size_t NW = (size_t)DMODEL * DMODEL;
  const size_t chunks = (NX + 4 * NW) / 8;
  for (size_t ci = (size_t)blockIdx.x * 256 + threadIdx.x; ci < chunks;
       ci += (size_t)gridDim.x * 256) {
    const size_t off = ci * 8;
    const float* src;
    size_t so;
    if (off < NX) { src = x; so = off; }
    else {
      size_t rem = off - NX;
      if (rem < NW) { src = wq; so = rem; }
      else if (rem < 2 * NW) { src = wk; so = rem - NW; }
      else if (rem < 3 * NW) { src = wv; so = rem - 2 * NW; }
      else { src = wo; so = rem - 3 * NW; }
    }
    f32x4 a = *(const f32x4*)&src[so];
    f32x4 b = *(const f32x4*)&src[so + 4];
    bf16x8 o;
#pragma unroll
    for (int j = 0; j < 4; ++j) { o[j] = (short)f2bf(a[j]); o[j + 4] = (short)f2bf(b[j]); }
    *(bf16x8*)&dst[off] = o;
  }
}

// ---------------------------------------------------------------------------
// 2-phase QKV GEMM (R8 structure): C[4096,6144] = A @ Wcat^T.
// Epilogue writes COMPACT per-head buffers:
//   qb[4096][2048]           : Q pre-scaled by 1/sqrt(d)
//   kb[bh][2048][128]        : K dense rows (tile kt = contiguous 16 KB)
//   vb[bh][32][128][64]      : V tile-blocked (tile kt = contiguous 16 KB)
// ---------------------------------------------------------------------------
__global__ __launch_bounds__(512, 2) void gemm_qkv(const u16* __restrict__ A,
                                                   const u16* __restrict__ W,
                                                   u16* __restrict__ qb,
                                                   u16* __restrict__ kb,
                                                   u16* __restrict__ vb) {
  __shared__ u16 lds[57344];
  const int tid = threadIdx.x, w = tid >> 6, lane = tid & 63;
  const int wm = w >> 2, wn = w & 3;
  const int fr = lane & 15, g = lane >> 4, g4 = g * 4;

  const int xcd = blockIdx.x & 7, bi = blockIdx.x >> 3;
  const int mt = bi >> 2, nt = xcd * 4 + (bi & 3);
  const int m0 = mt * 256, n0 = nt * 192;

  const int xs0 = (g ^ (fr & 7)) * 8;
  const int xs1 = xs0 ^ 32;
  const int aRow = wm * 128 + fr;
  const int bRow = wn * 48 + fr;

  const int sr = tid >> 3;
  const int scc = ((tid & 7) ^ (sr & 7)) * 8;
  const u16* pA0  = A + (size_t)(m0 + sr) * DMODEL + scc;
  const u16* pA1  = A + (size_t)(m0 + 64 + sr) * DMODEL + scc;
  const u16* pB0  = W + (size_t)(n0 + sr) * DMODEL + scc;
  const u16* pB0b = W + (size_t)(n0 + 64 + sr) * DMODEL + scc;
  const u16* pB1  = W + (size_t)(n0 + 128 + sr) * DMODEL + scc;

#define SAH(h, t, c)                                                                   \
  { gl_lds16(pA0 + (size_t)(h) * 128 * DMODEL + (t) * 64,                              \
             &lds[(c) * 16384 + (h) * 8192 + w * 512]);                                \
    gl_lds16(pA1 + (size_t)(h) * 128 * DMODEL + (t) * 64,                              \
             &lds[(c) * 16384 + (h) * 8192 + 4096 + w * 512]); }
#define SBH0(t, c)                                                                     \
  { gl_lds16(pB0 + (size_t)(t) * 64, &lds[32768 + (c) * 12288 + w * 512]);             \
    gl_lds16(pB0b + (size_t)(t) * 64, &lds[32768 + (c) * 12288 + 4096 + w * 512]); }
#define SBH1(t, c)                                                                     \
  { gl_lds16(pB1 + (size_t)(t) * 64, &lds[32768 + (c) * 12288 + 8192 + w * 512]); }

#define RD_AL(c)                                                                       \
  { _Pragma("unroll") for (int m_ = 0; m_ < 4; ++m_) {                                 \
      af[m_][0] = *(const bf16x8*)&lds[(c) * 16384 + (aRow + m_ * 16) * 64 + xs0];     \
      af[m_][1] = *(const bf16x8*)&lds[(c) * 16384 + (aRow + m_ * 16) * 64 + xs1]; } }
#define RD_AH(c)                                                                       \
  { _Pragma("unroll") for (int m_ = 0; m_ < 4; ++m_) {                                 \
      af[m_][0] = *(const bf16x8*)&lds[(c) * 16384 + (aRow + 64 + m_ * 16) * 64 + xs0];\
      af[m_][1] = *(const bf16x8*)&lds[(c) * 16384 + (aRow + 64 + m_ * 16) * 64 + xs1]; } }
#define RD_B(c)                                                                        \
  { _Pragma("unroll") for (int n_ = 0; n_ < 3; ++n_) {                                 \
      bfr[n_][0] = *(const bf16x8*)&lds[32768 + (c) * 12288 + (bRow + n_ * 16) * 64 + xs0]; \
      bfr[n_][1] = *(const bf16x8*)&lds[32768 + (c) * 12288 + (bRow + n_ * 16) * 64 + xs1]; } }

#define MMQ(MB)                                                                        \
  { __builtin_amdgcn_s_setprio(1);                                                    \
    _Pragma("unroll") for (int kc_ = 0; kc_ < 2; ++kc_)                                \
      _Pragma("unroll") for (int m_ = 0; m_ < 4; ++m_)                                 \
        _Pragma("unroll") for (int n_ = 0; n_ < 3; ++n_)                               \
          acc[(MB) + m_][n_] = MFMA16(af[m_][kc_], bfr[n_][kc_], acc[(MB) + m_][n_]);  \
    __builtin_amdgcn_s_setprio(0); }

  bf16x8 af[4][2], bfr[3][2];
  f32x4 acc[8][3];
#pragma unroll
  for (int i = 0; i < 8; ++i)
#pragma unroll
    for (int j = 0; j < 3; ++j) acc[i][j] = (f32x4){0.f, 0.f, 0.f, 0.f};

  SAH(0, 0, 0); SAH(1, 0, 0);
  SBH0(0, 0); SBH1(0, 0);
  SBH0(1, 1); SBH1(1, 1);
  VMC3; BAR;

#pragma unroll 1
  for (int i = 0; i < 15; ++i) {
    const int t0 = 2 * i;
    RD_AL(0); RD_B(0); SAH(0, t0 + 1, 1); SAH(1, t0 + 1, 1);
    FEN; BAR; MMQ(0); FEN; BAR;
    RD_AH(0); SBH0(t0 + 2, 0); SBH1(t0 + 2, 0);
    VMC3; BAR; MMQ(4); FEN; BAR;
    RD_AL(1); RD_B(1); SAH(0, t0 + 2, 0); SAH(1, t0 + 2, 0);
    FEN; BAR; MMQ(0); FEN; BAR;
    RD_AH(1); SBH0(t0 + 3, 1); SBH1(t0 + 3, 1);
    VMC3; BAR; MMQ(4); FEN; BAR;
  }
  RD_AL(0); RD_B(0); SAH(0, 31, 1); SAH(1, 31, 1);
  FEN; BAR; MMQ(0); FEN; BAR;
  RD_AH(0);
  VMC0; BAR; MMQ(4); FEN; BAR;
  RD_AL(1); RD_B(1);
  FEN; BAR; MMQ(0); FEN; BAR;
  RD_AH(1);
  FEN; BAR; MMQ(4);

#pragma unroll
  for (int mi = 0; mi < 8; ++mi)
#pragma unroll
    for (int ni = 0; ni < 3; ++ni) {
      const int row0 = m0 + wm * 128 + mi * 16 + g4;
      const int cg = n0 + wn * 48 + ni * 16 + fr;
      const int bb = row0 >> 11, tl = row0 & 2047;
      if (cg < DMODEL) {
        // Q, pre-scaled
#pragma unroll
        for (int r = 0; r < 4; ++r)
          qb[(size_t)(row0 + r) * DMODEL + cg] = f2bf(acc[mi][ni][r] * SC);
      } else if (cg < 2 * DMODEL) {
        // K -> compact [bh][t][128]
        const int cc = cg - DMODEL;
        const int hh = cc >> 7, d = cc & 127;
        const size_t kbase = (size_t)(bb * NHEADS + hh) * T_SEQ * HDIM;
#pragma unroll
        for (int r = 0; r < 4; ++r)
          kb[kbase + (size_t)(tl + r) * HDIM + d] = f2bf(acc[mi][ni][r]);
      } else {
        // V -> tile-blocked [bh][kt][d][64]
        const int cc = cg - 2 * DMODEL;
        const int hh = cc >> 7, d = cc & 127;
        u16x4 w4;
#pragma unroll
        for (int r = 0; r < 4; ++r) w4[r] = f2bf(acc[mi][ni][r]);
        *(u16x4*)&vb[(size_t)(bb * NHEADS + hh) * T_SEQ * HDIM + (size_t)(tl >> 6) * 8192 +
                     d * 64 + (tl & 63)] = w4;
      }
    }
#undef SAH
#undef SBH0
#undef SBH1
#undef RD_AL
#undef RD_AH
#undef RD_B
#undef MMQ
}

// ---------------------------------------------------------------------------
// 2-phase out-proj GEMM (unchanged, known-good R8).
// ---------------------------------------------------------------------------
__global__ __launch_bounds__(512, 2) void gemm_out(const u16* __restrict__ A,
                                                   const u16* __restrict__ W0,
                                                   float* __restrict__ outf) {
  __shared__ u16 lds2[49152];
  const int tid = threadIdx.x, w = tid >> 6, lane = tid & 63;
  const int wm = w >> 2, wn = w & 3;
  const int fr = lane & 15, g = lane >> 4, g4 = g * 4;

  const int xcd = blockIdx.x & 7, bi = blockIdx.x >> 3;
  const int mt = bi >> 1, nt = xcd * 2 + (bi & 1);
  const int m0 = mt * 256, n0 = nt * 128;

  const int xs0 = (g ^ (fr & 7)) * 8;
  const int xs1 = xs0 ^ 32;
  const int aRow = wm * 128 + fr;
  const int bRow = wn * 32 + fr;

  const int sr = tid >> 3;
  const int scc = ((tid & 7) ^ (sr & 7)) * 8;
  const u16* pA0  = A + (size_t)(m0 + sr) * DMODEL + scc;
  const u16* pA1  = A + (size_t)(m0 + 64 + sr) * DMODEL + scc;
  const u16* pB0  = W0 + (size_t)(n0 + sr) * DMODEL + scc;
  const u16* pB0b = W0 + (size_t)(n0 + 64 + sr) * DMODEL + scc;

#define S2A(h, t, c)                                                                   \
  { gl_lds16(pA0 + (size_t)(h) * 128 * DMODEL + (t) * 64,                              \
             &lds2[(c) * 16384 + (h) * 8192 + w * 512]);                               \
    gl_lds16(pA1 + (size_t)(h) * 128 * DMODEL + (t) * 64,                              \
             &lds2[(c) * 16384 + (h) * 8192 + 4096 + w * 512]); }
#define S2B(t, c)                                                                      \
  { gl_lds16(pB0 + (size_t)(t) * 64, &lds2[32768 + (c) * 8192 + w * 512]);             \
    gl_lds16(pB0b + (size_t)(t) * 64, &lds2[32768 + (c) * 8192 + 4096 + w * 512]); }

#define R2AL(c)                                                                        \
  { _Pragma("unroll") for (int m_ = 0; m_ < 4; ++m_) {                                 \
      af[m_][0] = *(const bf16x8*)&lds2[(c) * 16384 + (aRow + m_ * 16) * 64 + xs0];    \
      af[m_][1] = *(const bf16x8*)&lds2[(c) * 16384 + (aRow + m_ * 16) * 64 + xs1]; } }
#define R2AH(c)                                                                        \
  { _Pragma("unroll") for (int m_ = 0; m_ < 4; ++m_) {                                 \
      af[m_][0] = *(const bf16x8*)&lds2[(c) * 16384 + (aRow + 64 + m_ * 16) * 64 + xs0]; \
      af[m_][1] = *(const bf16x8*)&lds2[(c) * 16384 + (aRow + 64 + m_ * 16) * 64 + xs1]; } }
#define R2B(c)                                                                         \
  { _Pragma("unroll") for (int n_ = 0; n_ < 2; ++n_) {                                 \
      bfr[n_][0] = *(const bf16x8*)&lds2[32768 + (c) * 8192 + (bRow + n_ * 16) * 64 + xs0]; \
      bfr[n_][1] = *(const bf16x8*)&lds2[32768 + (c) * 8192 + (bRow + n_ * 16) * 64 + xs1]; } }

#define M2(MB)                                                                         \
  { __builtin_amdgcn_s_setprio(1);                                                    \
    _Pragma("unroll") for (int kc_ = 0; kc_ < 2; ++kc_)                                \
      _Pragma("unroll") for (int m_ = 0; m_ < 4; ++m_)                                 \
        _Pragma("unroll") for (int n_ = 0; n_ < 2; ++n_)                               \
          acc[(MB) + m_][n_] = MFMA16(af[m_][kc_], bfr[n_][kc_], acc[(MB) + m_][n_]);  \
    __builtin_amdgcn_s_setprio(0); }

  bf16x8 af[4][2], bfr[2][2];
  f32x4 acc[8][2];
#pragma unroll
  for (int i = 0; i < 8; ++i)
#pragma unroll
    for (int j = 0; j < 2; ++j) acc[i][j] = (f32x4){0.f, 0.f, 0.f, 0.f};

  S2A(0, 0, 0); S2A(1, 0, 0);
  S2B(0, 0);
  S2B(1, 1);
  VMC2; BAR;

#pragma unroll 1
  for (int i = 0; i < 15; ++i) {
    const int t0 = 2 * i;
    R2AL(0); R2B(0); S2A(0, t0 + 1, 1); S2A(1, t0 + 1, 1);
    FEN; BAR; M2(0); FEN; BAR;
    R2AH(0); S2B(t0 + 2, 0);
    VMC2; BAR; M2(4); FEN; BAR;
    R2AL(1); R2B(1); S2A(0, t0 + 2, 0); S2A(1, t0 + 2, 0);
    FEN; BAR; M2(0); FEN; BAR;
    R2AH(1); S2B(t0 + 3, 1);
    VMC2; BAR; M2(4); FEN; BAR;
  }
  R2AL(0); R2B(0); S2A(0, 31, 1); S2A(1, 31, 1);
  FEN; BAR; M2(0); FEN; BAR;
  R2AH(0);
  VMC0; BAR; M2(4); FEN; BAR;
  R2AL(1); R2B(1);
  FEN; BAR; M2(0); FEN; BAR;
  R2AH(1);
  FEN; BAR; M2(4);

#pragma unroll
  for (int mi = 0; mi < 8; ++mi)
#pragma unroll
    for (int ni = 0; ni < 2; ++ni) {
      const int row0 = m0 + wm * 128 + mi * 16 + g4;
      const int c = n0 + wn * 32 + ni * 16 + fr;
#pragma unroll
      for (int r = 0; r < 4; ++r)
        outf[(size_t)(row0 + r) * DMODEL + c] = acc[mi][ni][r];
    }
#undef S2A
#undef S2B
#undef R2AL
#undef R2AH
#undef R2B
#undef M2
}

// ---------------------------------------------------------------------------
// Striped flash attention (R11 scheduling), COMPACT K/V layouts.
// QB=128, 8 waves, KVB=64. Grid (24,16,2). Even h: bx<16 -> partial
// qt=15-(bx>>1), part=bx&1 (part0 kv 0..15, part1 kv 16..2qt+1); bx16..23 ->
// direct qt=23-bx. Odd h: bx<16 -> qt=15-bx banded.
// qb[4096][2048] (Q pre-scaled), kb[bh][t][128], vb[bh][kt][d][64]:
// each KV tile is one contiguous 16 KB block for K and for V.
// gl_lds dbuf, XOR granule swizzle, 1 barrier/iter, defer-max thr 8 (scaled).
// LDS 80 KB -> 2 blocks/CU.
// ---------------------------------------------------------------------------
#define QB 128
#define KVB 64

__global__ __launch_bounds__(512, 4) void attn_kernel(const u16* __restrict__ qb,
                                                      const u16* __restrict__ kb,
                                                      const u16* __restrict__ vb,
                                                      u16* __restrict__ op,
                                                      u16* __restrict__ pO,
                                                      float* __restrict__ pm,
                                                      float* __restrict__ pl) {
  __shared__ u16 lds[40960];  // 80 KB

  const int bx = blockIdx.x, h = blockIdx.y, b = blockIdx.z;
  const bool isglobal = (h & 1) == 0;
  int qt, klo, khi, part = 0;
  bool partial = false;
  if (isglobal) {
    if (bx < 16) {
      qt = 15 - (bx >> 1);
      part = bx & 1;
      partial = true;
      if (part == 0) { klo = 0; khi = 15; } else { klo = 16; khi = 2 * qt + 1; }
    } else {
      qt = 23 - bx;  // 0..7
      klo = 0; khi = 2 * qt + 1;
    }
  } else {
    if (bx >= 16) return;
    qt = 15 - bx;
    const int lo_ = qt * QB - (WINDOW - 1);
    klo = lo_ > 0 ? (lo_ >> 6) : 0;
    khi = 2 * qt + 1;
  }

  const int tid = threadIdx.x, wave = tid >> 6, lane = tid & 63;
  const int fr = lane & 15, g = lane >> 4, g4 = g * 4;
  const int xk = fr & 7;
  const int q0 = qt * QB;
  const int bh = b * NHEADS + h;
  const size_t basek = (size_t)bh * T_SEQ * HDIM;  // kb / vb head base
  const size_t baseo = (size_t)b * T_SEQ * DMODEL + (size_t)h * HDIM;

  // Q fragments (B-operand of swapped QK; row = fr = q-row); pre-scaled by SC
  bf16x8 qf[4];
  {
    const int qrow = q0 + wave * 16 + fr;
#pragma unroll
    for (int ds = 0; ds < 4; ++ds)
      qf[ds] = *(const bf16x8*)&qb[(size_t)b * T_SEQ * DMODEL + (size_t)qrow * DMODEL +
                                   (size_t)h * HDIM + ds * 32 + g * 8];
  }

  float mrun = -1e30f, lrun = 0.f;
  f32x4 o[8];
#pragma unroll
  for (int dt = 0; dt < 8; ++dt) o[dt] = (f32x4){0.f, 0.f, 0.f, 0.f};

  // gl_lds staging constants (pre-swizzled per-lane sources, contiguous tiles)
  const int j0 = wave * 2, j1 = wave * 2 + 1;
  const int gi0 = j0 * 64 + lane, gi1 = j1 * 64 + lane;
  const int kr0 = gi0 >> 4, kc0 = (gi0 & 15) ^ (kr0 & 7);
  const int kr1 = gi1 >> 4, kc1 = (gi1 & 15) ^ (kr1 & 7);
  const u16* pK0 = kb + basek + (size_t)kr0 * HDIM + kc0 * 8;
  const u16* pK1 = kb + basek + (size_t)kr1 * HDIM + kc1 * 8;
  const int d0 = gi0 >> 3, vs0 = (gi0 & 7) ^ (d0 & 7);
  const int d1 = gi1 >> 3, vs1 = (gi1 & 7) ^ (d1 & 7);
  const u16* pV0 = vb + basek + (size_t)d0 * 64 + vs0 * 8;
  const u16* pV1 = vb + basek + (size_t)d1 * 64 + vs1 * 8;

#define STAGE(KT, c)                                                                   \
  { gl_lds16(pK0 + (size_t)(KT) * 8192, &lds[(c) * 8192 + j0 * 512]);                  \
    gl_lds16(pK1 + (size_t)(KT) * 8192, &lds[(c) * 8192 + j1 * 512]);                  \
    gl_lds16(pV0 + (size_t)(KT) * 8192, &lds[16384 + (c) * 8192 + j0 * 512]);          \
    gl_lds16(pV1 + (size_t)(KT) * 8192, &lds[16384 + (c) * 8192 + j1 * 512]); }

  u16* Pw = &lds[32768 + wave * 1024];
  const int qg = q0 + wave * 16 + fr;

  STAGE(klo, klo & 1);
  VMC0; BAR;

  for (int kt = klo; kt <= khi; ++kt) {
    const int c = kt & 1;
    const bool more = kt < khi;
    if (more) STAGE(kt + 1, c ^ 1);
    const u16* Kc = &lds[c * 8192];
    const u16* Vc = &lds[16384 + c * 8192];

    // ---- S = K Q^T (swapped): lane holds q=fr, kv = kk*16 + g4 + reg ----
    f32x4 s[4];
    __builtin_amdgcn_s_setprio(1);
#pragma unroll
    for (int kk = 0; kk < 4; ++kk) {
      f32x4 a = (f32x4){0.f, 0.f, 0.f, 0.f};
#pragma unroll
      for (int ds = 0; ds < 4; ++ds) {
        const int r = kk * 16 + fr;
        bf16x8 kf = *(const bf16x8*)&Kc[r * 128 + (((ds * 4 + g) ^ xk) << 3)];
        a = MFMA16(kf, qf[ds], a);
      }
      s[kk] = a;
    }
    __builtin_amdgcn_s_setprio(0);

    // ---- masked online softmax (scaled domain), defer-max ----
    float sv[16];
    float pmax = -1e30f;
#pragma unroll
    for (int kk = 0; kk < 4; ++kk)
#pragma unroll
      for (int reg = 0; reg < 4; ++reg) {
        const int cg = kt * KVB + kk * 16 + g4 + reg;
        const bool allowed = (cg <= qg) && (isglobal || cg >= qg - (WINDOW - 1));
        const float v = allowed ? s[kk][reg] : -1e30f;
        sv[kk * 4 + reg] = v;
        pmax = fmaxf(pmax, v);
      }
    pmax = fmaxf(pmax, __shfl_xor(pmax, 16, 64));
    pmax = fmaxf(pmax, __shfl_xor(pmax, 32, 64));
    const bool resc = !__all(pmax - mrun <= 8.0f);  // T13
    float fac = 1.f;
    if (resc) {
      const float nm = fmaxf(mrun, pmax);
      fac = __expf(mrun - nm);
      mrun = nm;
    }
    float rs = 0.f;
    u16 pb[16];
#pragma unroll
    for (int i = 0; i < 16; ++i) {
      const float p = (sv[i] > -5e29f) ? __expf(sv[i] - mrun) : 0.f;
      rs += p;
      pb[i] = f2bf(p);
    }
    rs += __shfl_xor(rs, 16, 64);
    rs += __shfl_xor(rs, 32, 64);
    lrun = lrun * fac + rs;

    // P -> per-wave LDS (swizzled 8B writes; row = q = fr)
#pragma unroll
    for (int kk = 0; kk < 4; ++kk) {
      u16x4 wv;
      wv[0] = pb[kk * 4]; wv[1] = pb[kk * 4 + 1]; wv[2] = pb[kk * 4 + 2]; wv[3] = pb[kk * 4 + 3];
      *(u16x4*)&Pw[fr * 64 + (((2 * kk + (g >> 1)) ^ xk) << 3) + (g & 1) * 4] = wv;
    }

    if (resc) {
      float ff[4];
#pragma unroll
      for (int r = 0; r < 4; ++r) ff[r] = __shfl(fac, g4 + r, 64);
#pragma unroll
      for (int dt = 0; dt < 8; ++dt)
#pragma unroll
        for (int r = 0; r < 4; ++r) o[dt][r] *= ff[r];
    }

    // ---- O += P V ----
    bf16x8 pf0 = *(const bf16x8*)&Pw[fr * 64 + ((g ^ xk) << 3)];
    bf16x8 pf1 = *(const bf16x8*)&Pw[fr * 64 + (((4 + g) ^ xk) << 3)];
    __builtin_amdgcn_s_setprio(1);
#pragma unroll
    for (int dt = 0; dt < 8; ++dt) {
      const int d = dt * 16 + fr;
      bf16x8 vf0 = *(const bf16x8*)&Vc[d * 64 + ((g ^ xk) << 3)];
      bf16x8 vf1 = *(const bf16x8*)&Vc[d * 64 + (((4 + g) ^ xk) << 3)];
      o[dt] = MFMA16(pf0, vf0, o[dt]);
      o[dt] = MFMA16(pf1, vf1, o[dt]);
    }
    __builtin_amdgcn_s_setprio(0);

    FEN;
    VMC0;
    BAR;
  }

  if (!partial) {
    const float inv = 1.0f / lrun;
    float iv[4];
#pragma unroll
    for (int r = 0; r < 4; ++r) iv[r] = __shfl(inv, g4 + r, 64);
#pragma unroll
    for (int r = 0; r < 4; ++r) {
      const int qrow = q0 + wave * 16 + g4 + r;
#pragma unroll
      for (int dt = 0; dt < 8; ++dt)
        op[baseo + (size_t)qrow * DMODEL + dt * 16 + fr] = f2bf(o[dt][r] * iv[r]);
    }
  } else {
    const int sidx = (((b * 8 + (h >> 1)) * 8 + (qt - 8)) << 1) + part;
    const size_t sb = (size_t)sidx * QB;
#pragma unroll
    for (int r = 0; r < 4; ++r) {
      const size_t row = sb + wave * 16 + g4 + r;
#pragma unroll
      for (int dt = 0; dt < 8; ++dt)
        pO[row * HDIM + dt * 16 + fr] = f2bf(o[dt][r]);
    }
    if (lane < 16) {
      pm[sb + wave * 16 + lane] = mrun;
      pl[sb + wave * 16 + lane] = lrun;
    }
  }
#undef STAGE
}

// ---------------------------------------------------------------------------
// Merge two partials per (b, even h, qt>=8). Grid 128 x 256 thr. Scaled dom.
// ---------------------------------------------------------------------------
__global__ __launch_bounds__(256) void merge_kernel(const u16* __restrict__ pO,
                                                    const float* __restrict__ pm,
                                                    const float* __restrict__ pl,
                                                    u16* __restrict__ op) {
  const int x = blockIdx.x;  // 0..127 = (b*8 + eh)*8 + qt8
  const int qt8 = x & 7, eh = (x >> 3) & 7, b = x >> 6;
  const int h = eh * 2, qt = 8 + qt8;
  const int s0 = x * 2, s1 = s0 + 1;

  for (int i = 0; i < 8; ++i) {
    const int vidx = threadIdx.x + i * 256;  // 0..2047
    const int row = vidx >> 4, d8 = (vidx & 15) * 8;
    const float m0 = pm[s0 * QB + row], m1 = pm[s1 * QB + row];
    const float l0 = pl[s0 * QB + row], l1 = pl[s1 * QB + row];
    const float m = fmaxf(m0, m1);
    const float w0 = __expf(m0 - m), w1 = __expf(m1 - m);
    const float inv = 1.0f / (l0 * w0 + l1 * w1);
    bf16x8 a = *(const bf16x8*)&pO[((size_t)s0 * QB + row) * HDIM + d8];
    bf16x8 c = *(const bf16x8*)&pO[((size_t)s1 * QB + row) * HDIM + d8];
    bf16x8 r;
#pragma unroll
    for (int j = 0; j < 8; ++j)
      r[j] = (short)f2bf((bf2f((u16)a[j]) * w0 + bf2f((u16)c[j]) * w1) * inv);
    *(bf16x8*)&op[((size_t)(b * T_SEQ + qt * QB + row)) * DMODEL + h * HDIM + d8] = r;
  }
}

// ---------------------------------------------------------------------------
extern "C" void kernel_launch(void* const* d_in, const int* in_sizes, int n_in,
                              void* d_out, int out_size, void* d_ws, size_t ws_size,
                              hipStream_t stream) {
  (void)in_sizes; (void)n_in; (void)out_size; (void)ws_size;
  const float* x  = (const float*)d_in[0];
  const float* Wq = (const float*)d_in[1];
  const float* Wk = (const float*)d_in[2];
  const float* Wv = (const float*)d_in[3];
  const float* Wo = (const float*)d_in[4];

  const size_t NX = (size_t)MROWS * DMODEL;
  const size_t NW = (size_t)DMODEL * DMODEL;
  u16* ws  = (u16*)d_ws;
  u16* xb  = ws;                 // bf16 x; later attention output
  u16* wqb = ws + NX;            // [wq|wk|wv] contiguous = Wcat[6144][2048]
  u16* wkb = wqb + NW;
  u16* wvb = wkb + NW;
  u16* wob = wvb + NW;
  u16* qbb = wob + NW;           // qb [4096][2048]
  u16* kbb = qbb + NX;           // kb [32][2048][128]
  u16* vbb = kbb + NX;           // vb [32][32][128][64]

  // partials reuse dead wq/wk region: 256 slots x 128 rows x 128 d
  u16*   pO = wqb;
  float* pm = (float*)(wqb + (size_t)256 * QB * HDIM);
  float* pl = pm + 256 * QB;

  convert_all<<<2048, 256, 0, stream>>>(x, Wq, Wk, Wv, Wo, ws);

  gemm_qkv<<<512, 512, 0, stream>>>(xb, wqb, qbb, kbb, vbb);

  attn_kernel<<<dim3(24, NHEADS, 2), 512, 0, stream>>>(qbb, kbb, vbb, xb, pO, pm, pl);

  merge_kernel<<<128, 256, 0, stream>>>(pO, pm, pl, xb);

  gemm_out<<<256, 512, 0, stream>>>(xb, wob, (float*)d_out);
}